// Round 6
// baseline (66.938 us; speedup 1.0000x reference)
//
#include <hip/hip_runtime.h>

#define B_IMG 32
#define N_A   200000
#define N_C   10000

#define NCH    60                  // bbox anchor chunks per image
#define CHUNK  3334                // ceil(N_A / NCH)
#define NCC    4                   // cls chunks per image
#define CCHUNK (N_C / NCC)         // 2500
#define SLOTS  64                  // 60 bbox + 4 cls slots per image
#define GRID   (B_IMG * SLOTS)     // 2048 blocks = 8 per CU exactly

// ws layout (doubles):
// [0, 1920)        bbox focal partial  [j*NCH + ch]
// [1920, 3840)     pos-count partial   [j*NCH + ch]
// [3840, 3968)     cls focal partial   [j*NCC + cc]
// byte 31744:      unsigned int completion counter (memset to 0 each call)
#define WS_FOCAL 0
#define WS_CNT   (B_IMG * NCH)
#define WS_CLS   (2 * B_IMG * NCH)
#define WS_CTR_BYTES ((size_t)(2 * B_IMG * NCH + B_IMG * NCC) * 8)

typedef float f4 __attribute__((ext_vector_type(4)));

// c = sigmoid(x); t=1: 0.25*(1-c)^2*(-log c); t=0: 0.75*c^2*(-log(1-c))
// -log(c) = log(1+e), e = exp(-x);  -log(1-c) = x + log(1+e);  1-c = e*c
__device__ __forceinline__ float focal_elem(float x, bool t) {
    float e = __expf(-x);
    float r = __builtin_amdgcn_rcpf(1.0f + e);   // c
    float L = __logf(1.0f + e);                  // softplus(-x)
    if (t) { float om = e * r; return 0.25f * om * om * L; }
    else   { return 0.75f * r * r * (x + L); }
}

__device__ __forceinline__ double wave_red(double v) {
#pragma unroll
    for (int o = 32; o; o >>= 1) v += __shfl_down(v, o, 64);
    return v;
}

// block = (j, slot): slot < 60 -> bbox chunk; slot >= 60 -> cls chunk (slot-60)
__global__ __launch_bounds__(256) void fused_kernel(
    const float* __restrict__ cls, const float* __restrict__ bd,
    const float* __restrict__ anc, const float* __restrict__ ann,
    const float* __restrict__ reg, double* __restrict__ ws,
    unsigned int* __restrict__ ctr, float* __restrict__ out)
{
    const int tid = threadIdx.x;
    const int lane = tid & 63, wv = tid >> 6;
    const int j  = blockIdx.x >> 6;     // image
    const int ch = blockIdx.x & 63;     // slot
    __shared__ double sred[2][4];
    __shared__ int s_last;
    const f4* __restrict__ anc4 = (const f4*)anc;

    if (ch < NCH) {
        const int a0 = ch * CHUNK;
        const int a1 = min(a0 + CHUNK, N_A);
        const float b0 = ann[j*7+0], b1 = ann[j*7+1], b2 = ann[j*7+2], b3 = ann[j*7+3];
        const float barea = (b2 - b0) * (b3 - b1);
        const float* __restrict__ bdr = bd + (size_t)j * N_A;

        float fsum = 0.0f, cnt = 0.0f;
        for (int i = a0 + tid; i < a1; i += 256) {
            const f4 av = anc4[i];                           // x0,y0,x1,y1
            float iw = fmaxf(fminf(av.z, b2) - fmaxf(av.x, b0), 0.0f);
            float ih = fmaxf(fminf(av.w, b3) - fmaxf(av.y, b1), 0.0f);
            float inter = iw * ih;
            float ua = fmaxf((av.z - av.x) * (av.w - av.y) + barea - inter, 1e-8f);
            bool pos = (2.0f * inter >= ua);                 // inter/ua >= 0.5
            fsum += focal_elem(bdr[i], pos);
            cnt  += pos ? 1.0f : 0.0f;
        }
        double fv = wave_red((double)fsum);
        double cv = wave_red((double)cnt);
        if (lane == 0) { sred[0][wv] = fv; sred[1][wv] = cv; }
        __syncthreads();
        if (tid == 0) {
            ws[WS_FOCAL + j * NCH + ch] = sred[0][0] + sred[0][1] + sred[0][2] + sred[0][3];
            ws[WS_CNT   + j * NCH + ch] = sred[1][0] + sred[1][1] + sred[1][2] + sred[1][3];
        }
    } else {
        const int cc = ch - NCH;            // cls chunk
        const int c0 = cc * CCHUNK;
        const int n0 = (int)ann[j*7+4], n1 = (int)ann[j*7+5], n2 = (int)ann[j*7+6];
        const float* __restrict__ cj = cls + (size_t)j * N_C;
        float fsum = 0.0f;
        for (int i = c0 + tid; i < c0 + CCHUNK; i += 256) {
            bool t = (i == n0) || (i == n1) || (i == n2);
            fsum += focal_elem(cj[i], t);
        }
        double v = wave_red((double)fsum);
        if (lane == 0) sred[0][wv] = v;
        __syncthreads();
        if (tid == 0)
            ws[WS_CLS + j * NCC + cc] = sred[0][0] + sred[0][1] + sred[0][2] + sred[0][3];
    }

    // fan-in: last block to finish does the final reduction
    if (tid == 0) {
        __threadfence();                                   // release ws partials
        unsigned int old = atomicAdd(ctr, 1u);
        s_last = (old == GRID - 1) ? 1 : 0;
    }
    __syncthreads();
    if (!s_last) return;
    __threadfence();                                       // acquire all ws partials

    int t = tid;
    double cl = 0.0, bl = 0.0, rl = 0.0;
    if (t < B_IMG) {
        int jj = t;
        double fsum = 0.0, npos = 0.0, csum = 0.0;
        for (int c = 0; c < NCH; ++c) {
            fsum += ws[WS_FOCAL + jj * NCH + c];
            npos += ws[WS_CNT   + jj * NCH + c];
        }
        for (int c = 0; c < NCC; ++c) csum += ws[WS_CLS + jj * NCC + c];
        cl = csum / (double)N_C;
        bl = fsum / (double)N_A;

        float b0 = ann[jj*7+0], b1 = ann[jj*7+1], b2 = ann[jj*7+2], b3 = ann[jj*7+3];
        float gw_raw = b2 - b0, gh_raw = b3 - b1;
        float gx = b0 + 0.5f * gw_raw, gy = b1 + 0.5f * gh_raw;
        float gw = fmaxf(gw_raw, 1.0f), gh = fmaxf(gh_raw, 1.0f);
        double s[2];
#pragma unroll
        for (int p = 0; p < 2; ++p) {
            float x0 = anc[p*4+0], y0 = anc[p*4+1], x1 = anc[p*4+2], y1 = anc[p*4+3];
            float aw = x1 - x0, ah = y1 - y0;
            float ax = x0 + 0.5f * aw, ay = y0 + 0.5f * ah;
            float tg[4];
            tg[0] = ((gx - ax) / aw) / 0.1f;
            tg[1] = ((gy - ay) / ah) / 0.1f;
            tg[2] = logf(gw / aw) / 0.2f;
            tg[3] = logf(gh / ah) / 0.2f;
            const float* rj = reg + (size_t)jj * N_A * 4 + p * 4;
            double ssum = 0.0;
#pragma unroll
            for (int k = 0; k < 4; ++k) {
                float d = fabsf(tg[k] - rj[k]);
                float v = (d <= (1.0f / 9.0f)) ? (0.5f * 9.0f * d * d) : (d - 0.5f / 9.0f);
                ssum += (double)v;
            }
            s[p] = ssum;
        }
        double rlv = (((double)N_A - npos) * s[0] + npos * s[1]) / (4.0 * (double)N_A);
        rl = (npos > 0.0) ? rlv : 0.0;
    }
    if (tid < 64) {
        cl = wave_red(cl);
        bl = wave_red(bl);
        rl = wave_red(rl);
        if (tid == 0) {
            out[0] = (float)(cl / B_IMG);
            out[1] = (float)(bl / B_IMG);
            out[2] = (float)(rl / B_IMG);
        }
    }
}

extern "C" void kernel_launch(void* const* d_in, const int* in_sizes, int n_in,
                              void* d_out, int out_size, void* d_ws, size_t ws_size,
                              hipStream_t stream) {
    const float* cls = (const float*)d_in[0];   // (32, 10000)
    const float* reg = (const float*)d_in[1];   // (32, 200000, 4)
    const float* bd  = (const float*)d_in[2];   // (32, 200000)
    const float* anc = (const float*)d_in[3];   // (1, 200000, 4)
    const float* ann = (const float*)d_in[4];   // (32, 1, 7)
    float* out = (float*)d_out;                 // 3 floats
    double* ws = (double*)d_ws;
    unsigned int* ctr = (unsigned int*)((char*)d_ws + WS_CTR_BYTES);

    hipMemsetAsync(ctr, 0, sizeof(unsigned int), stream);
    hipLaunchKernelGGL(fused_kernel, dim3(GRID), dim3(256), 0, stream,
                       cls, bd, anc, ann, reg, ws, ctr, out);
}

// Round 7
// 22.171 us; speedup vs baseline: 3.0192x; 3.0192x over previous
//
#include <hip/hip_runtime.h>

#define B_IMG 32
#define N_A   200000
#define N_C   10000

#define NCH    60                  // bbox chunks per image (units of 256; last takes tail)
#define BCH    3328                // 13 * 256
#define NCC    4                   // cls chunks per image
#define CCH    2560                // 10 * 256
#define SLOTS  64                  // 60 bbox + 4 cls
#define GRID   (B_IMG * SLOTS)     // 2048 = exactly 8 blocks/CU

// ws layout (doubles):
// [0, 1920)        bbox focal partial  [j*NCH + ch]
// [1920, 3840)     pos-count partial   [j*NCH + ch]
// [3840, 3968)     cls focal partial   [j*NCC + cc]
#define WS_FOCAL 0
#define WS_CNT   (B_IMG * NCH)
#define WS_CLS   (2 * B_IMG * NCH)

typedef float f4 __attribute__((ext_vector_type(4)));

// c = sigmoid(x); t=1: 0.25*(1-c)^2*(-log c); t=0: 0.75*c^2*(-log(1-c))
// -log(c) = log(1+e), e = exp(-x);  -log(1-c) = x + log(1+e);  1-c = e*c
__device__ __forceinline__ float focal_elem(float x, bool t) {
    float e = __expf(-x);
    float r = __builtin_amdgcn_rcpf(1.0f + e);   // c
    float L = __logf(1.0f + e);                  // softplus(-x)
    if (t) { float om = e * r; return 0.25f * om * om * L; }
    else   { return 0.75f * r * r * (x + L); }
}

__device__ __forceinline__ double wave_red(double v) {
#pragma unroll
    for (int o = 32; o; o >>= 1) v += __shfl_down(v, o, 64);
    return v;
}

// block = (j, slot): slot < 60 -> bbox chunk; slot >= 60 -> cls chunk (slot-60)
__global__ __launch_bounds__(256) void main_kernel(
    const float* __restrict__ cls, const float* __restrict__ bd,
    const float* __restrict__ anc, const float* __restrict__ ann,
    double* __restrict__ ws)
{
    const int tid = threadIdx.x;
    const int lane = tid & 63, wv = tid >> 6;
    const int j  = blockIdx.x >> 6;     // image
    const int ch = blockIdx.x & 63;     // slot
    __shared__ double sred[2][4];
    const f4* __restrict__ anc4 = (const f4*)anc;

    if (ch < NCH) {
        const int a0 = ch * BCH;
        const int a1 = (ch == NCH - 1) ? N_A : (a0 + BCH);   // last chunk: 3648
        const int nfull = (a1 - a0) >> 8;                    // 13 (or 14)
        const float b0 = ann[j*7+0], b1 = ann[j*7+1], b2 = ann[j*7+2], b3 = ann[j*7+3];
        const float barea = (b2 - b0) * (b3 - b1);
        const float* __restrict__ bdr = bd + (size_t)j * N_A;

        float fsum = 0.0f, cnt = 0.0f;
        const int base = a0 + tid;
#pragma unroll 4
        for (int u = 0; u < nfull; ++u) {
            const int i = base + (u << 8);
            const f4 av = anc4[i];                           // x0,y0,x1,y1
            float iw = fmaxf(fminf(av.z, b2) - fmaxf(av.x, b0), 0.0f);
            float ih = fmaxf(fminf(av.w, b3) - fmaxf(av.y, b1), 0.0f);
            float inter = iw * ih;
            float ua = fmaxf((av.z - av.x) * (av.w - av.y) + barea - inter, 1e-8f);
            bool pos = (2.0f * inter >= ua);                 // inter/ua >= 0.5
            fsum += focal_elem(bdr[i], pos);
            cnt  += pos ? 1.0f : 0.0f;
        }
        {   // tail (only last chunk, 64 lanes)
            const int i = base + (nfull << 8);
            if (i < a1) {
                const f4 av = anc4[i];
                float iw = fmaxf(fminf(av.z, b2) - fmaxf(av.x, b0), 0.0f);
                float ih = fmaxf(fminf(av.w, b3) - fmaxf(av.y, b1), 0.0f);
                float inter = iw * ih;
                float ua = fmaxf((av.z - av.x) * (av.w - av.y) + barea - inter, 1e-8f);
                bool pos = (2.0f * inter >= ua);
                fsum += focal_elem(bdr[i], pos);
                cnt  += pos ? 1.0f : 0.0f;
            }
        }
        double fv = wave_red((double)fsum);
        double cv = wave_red((double)cnt);
        if (lane == 0) { sred[0][wv] = fv; sred[1][wv] = cv; }
        __syncthreads();
        if (tid == 0) {
            ws[WS_FOCAL + j * NCH + ch] = sred[0][0] + sred[0][1] + sred[0][2] + sred[0][3];
            ws[WS_CNT   + j * NCH + ch] = sred[1][0] + sred[1][1] + sred[1][2] + sred[1][3];
        }
    } else {
        const int cc = ch - NCH;            // cls chunk
        const int c0 = cc * CCH;
        const int c1 = (cc == NCC - 1) ? N_C : (c0 + CCH);   // last: 2320
        const int nfull = (c1 - c0) >> 8;
        const int n0 = (int)ann[j*7+4], n1 = (int)ann[j*7+5], n2 = (int)ann[j*7+6];
        const float* __restrict__ cj = cls + (size_t)j * N_C;
        float fsum = 0.0f;
        const int base = c0 + tid;
#pragma unroll 4
        for (int u = 0; u < nfull; ++u) {
            const int i = base + (u << 8);
            bool t = (i == n0) || (i == n1) || (i == n2);
            fsum += focal_elem(cj[i], t);
        }
        {
            const int i = base + (nfull << 8);
            if (i < c1) {
                bool t = (i == n0) || (i == n1) || (i == n2);
                fsum += focal_elem(cj[i], t);
            }
        }
        double v = wave_red((double)fsum);
        if (lane == 0) sred[0][wv] = v;
        __syncthreads();
        if (tid == 0)
            ws[WS_CLS + j * NCC + cc] = sred[0][0] + sred[0][1] + sred[0][2] + sred[0][3];
    }
}

__global__ void final_kernel(
    const float* __restrict__ anc, const float* __restrict__ ann,
    const float* __restrict__ reg, const double* __restrict__ ws,
    float* __restrict__ out)
{
    int t = threadIdx.x;
    double cl = 0.0, bl = 0.0, rl = 0.0;
    if (t < B_IMG) {
        int j = t;
        double fsum = 0.0, npos = 0.0, csum = 0.0;
#pragma unroll 10
        for (int c = 0; c < NCH; ++c) {
            fsum += ws[WS_FOCAL + j * NCH + c];
            npos += ws[WS_CNT   + j * NCH + c];
        }
#pragma unroll
        for (int c = 0; c < NCC; ++c) csum += ws[WS_CLS + j * NCC + c];
        cl = csum / (double)N_C;
        bl = fsum / (double)N_A;

        float b0 = ann[j*7+0], b1 = ann[j*7+1], b2 = ann[j*7+2], b3 = ann[j*7+3];
        float gw_raw = b2 - b0, gh_raw = b3 - b1;
        float gx = b0 + 0.5f * gw_raw, gy = b1 + 0.5f * gh_raw;
        float gw = fmaxf(gw_raw, 1.0f), gh = fmaxf(gh_raw, 1.0f);
        double s[2];
#pragma unroll
        for (int p = 0; p < 2; ++p) {
            float x0 = anc[p*4+0], y0 = anc[p*4+1], x1 = anc[p*4+2], y1 = anc[p*4+3];
            float aw = x1 - x0, ah = y1 - y0;
            float ax = x0 + 0.5f * aw, ay = y0 + 0.5f * ah;
            float tg[4];
            tg[0] = ((gx - ax) / aw) / 0.1f;
            tg[1] = ((gy - ay) / ah) / 0.1f;
            tg[2] = logf(gw / aw) / 0.2f;
            tg[3] = logf(gh / ah) / 0.2f;
            const float* rj = reg + (size_t)j * N_A * 4 + p * 4;
            double ssum = 0.0;
#pragma unroll
            for (int k = 0; k < 4; ++k) {
                float d = fabsf(tg[k] - rj[k]);
                float v = (d <= (1.0f / 9.0f)) ? (0.5f * 9.0f * d * d) : (d - 0.5f / 9.0f);
                ssum += (double)v;
            }
            s[p] = ssum;
        }
        double rlv = (((double)N_A - npos) * s[0] + npos * s[1]) / (4.0 * (double)N_A);
        rl = (npos > 0.0) ? rlv : 0.0;
    }
    cl = wave_red(cl);
    bl = wave_red(bl);
    rl = wave_red(rl);
    if (t == 0) {
        out[0] = (float)(cl / B_IMG);
        out[1] = (float)(bl / B_IMG);
        out[2] = (float)(rl / B_IMG);
    }
}

extern "C" void kernel_launch(void* const* d_in, const int* in_sizes, int n_in,
                              void* d_out, int out_size, void* d_ws, size_t ws_size,
                              hipStream_t stream) {
    const float* cls = (const float*)d_in[0];   // (32, 10000)
    const float* reg = (const float*)d_in[1];   // (32, 200000, 4)
    const float* bd  = (const float*)d_in[2];   // (32, 200000)
    const float* anc = (const float*)d_in[3];   // (1, 200000, 4)
    const float* ann = (const float*)d_in[4];   // (32, 1, 7)
    float* out = (float*)d_out;                 // 3 floats
    double* ws = (double*)d_ws;

    hipLaunchKernelGGL(main_kernel, dim3(GRID), dim3(256), 0, stream,
                       cls, bd, anc, ann, ws);
    hipLaunchKernelGGL(final_kernel, dim3(1), dim3(64), 0, stream, anc, ann, reg, ws, out);
}